// Round 1
// baseline (6964.401 us; speedup 1.0000x reference)
//
#include <hip/hip_runtime.h>

#define NN 263
#define TT 24

static __device__ __forceinline__ float wred_sum(float v) {
  #pragma unroll
  for (int off = 32; off >= 1; off >>= 1) v += __shfl_xor(v, off, 64);
  return v;
}
static __device__ __forceinline__ float wred_max(float v) {
  #pragma unroll
  for (int off = 32; off >= 1; off >>= 1) v = fmaxf(v, __shfl_xor(v, off, 64));
  return v;
}

// ---------------------------------------------------------------------------
// Generic fp32 NT GEMM: C[m,n] = sum_k A[m,k]*W[n,k] (+bias[n])
// A: [M x K] row-major, W: [N x K] row-major, C: [M x ldc] (base pre-offset).
// 128x128 tile, BK=16, 256 threads, 8x8 micro-tile per thread.
// ---------------------------------------------------------------------------
__global__ __launch_bounds__(256) void gemm_nt(
    const float* __restrict__ A, const float* __restrict__ W,
    const float* __restrict__ bias, float* __restrict__ C,
    int M, int N, int K, int ldc)
{
  __shared__ float As[16][132];  // +4 pad keeps 16B alignment, breaks pow2 stride
  __shared__ float Bs[16][132];
  const int bm = blockIdx.x * 128;
  const int bn = blockIdx.y * 128;
  const int tid = threadIdx.x;
  const int tx = tid & 15, ty = tid >> 4;
  float acc[8][8];
  #pragma unroll
  for (int i = 0; i < 8; ++i)
    #pragma unroll
    for (int j = 0; j < 8; ++j) acc[i][j] = 0.f;

  for (int k0 = 0; k0 < K; k0 += 16) {
    #pragma unroll
    for (int l = 0; l < 2; ++l) {
      int idx = tid + l * 256;        // 0..511
      int m = idx >> 2;               // 0..127
      int kq = (idx & 3) << 2;        // 0,4,8,12
      int gm = bm + m; if (gm > M - 1) gm = M - 1;
      float4 av = *(const float4*)(A + (size_t)gm * K + k0 + kq);
      As[kq + 0][m] = av.x; As[kq + 1][m] = av.y;
      As[kq + 2][m] = av.z; As[kq + 3][m] = av.w;
      int gn = bn + m; if (gn > N - 1) gn = N - 1;
      float4 bv = *(const float4*)(W + (size_t)gn * K + k0 + kq);
      Bs[kq + 0][m] = bv.x; Bs[kq + 1][m] = bv.y;
      Bs[kq + 2][m] = bv.z; Bs[kq + 3][m] = bv.w;
    }
    __syncthreads();
    #pragma unroll
    for (int k = 0; k < 16; ++k) {
      float a[8], b[8];
      #pragma unroll
      for (int i = 0; i < 8; ++i) a[i] = As[k][ty * 8 + i];
      #pragma unroll
      for (int j = 0; j < 8; ++j) b[j] = Bs[k][tx * 8 + j];
      #pragma unroll
      for (int i = 0; i < 8; ++i)
        #pragma unroll
        for (int j = 0; j < 8; ++j) acc[i][j] = fmaf(a[i], b[j], acc[i][j]);
    }
    __syncthreads();
  }
  #pragma unroll
  for (int i = 0; i < 8; ++i) {
    int gm = bm + ty * 8 + i;
    if (gm >= M) break;
    float* crow = C + (size_t)gm * ldc + bn;
    #pragma unroll
    for (int j = 0; j < 8; ++j) {
      int gn = bn + tx * 8 + j;
      if (gn < N) {
        float v = acc[i][j];
        if (bias) v += bias[gn];
        crow[tx * 8 + j] = v;
      }
    }
  }
}

// ---------------------------------------------------------------------------
// lambda scalar: exp(sum(lq1*lk1)) - exp(sum(lq2*lk2)) + 0.2
// ---------------------------------------------------------------------------
__global__ void lam_kernel(const float* __restrict__ lq1, const float* __restrict__ lk1,
                           const float* __restrict__ lq2, const float* __restrict__ lk2,
                           float* __restrict__ out) {
  int lane = threadIdx.x;
  float v1 = lane < 32 ? lq1[lane] * lk1[lane] : 0.f;
  float v2 = lane < 32 ? lq2[lane] * lk2[lane] : 0.f;
  v1 = wred_sum(v1);
  v2 = wred_sum(v2);
  if (lane == 0) out[0] = expf(v1) - expf(v2) + 0.2f;
}

// ---------------------------------------------------------------------------
// Differential self-attention half: for (b,t,h,i) compute
// a_i[n,d] = softmax_m(q_i[n]·k_i[m] / sqrt(32)) @ v[m,d]
// qkv_s row: [q(256) | k(256) | v(256)], head h, half i (i*32 offset in q/k).
// K staged transposed in LDS (stride-1, conflict-free score reads);
// p broadcast via per-wave LDS row; v read from global (coalesced, L2-hot).
// ---------------------------------------------------------------------------
__global__ __launch_bounds__(256) void diff_attn(
    const float* __restrict__ qkv, float* __restrict__ aout)
{
  __shared__ float ks[32 * NN];
  __shared__ float prow[4 * 264];
  const int h = blockIdx.x & 3;
  const int bt = blockIdx.x >> 2;
  const int i = blockIdx.y;
  const int tid = threadIdx.x;
  const int lane = tid & 63;
  const int wave = tid >> 6;
  const float* base = qkv + (size_t)bt * NN * 768;
  for (int idx = tid; idx < NN * 32; idx += 256) {
    int m = idx >> 5, k = idx & 31;
    ks[k * NN + m] = base[(size_t)m * 768 + 256 + h * 64 + i * 32 + k];
  }
  __syncthreads();
  const float* vbase = base + 512 + h * 64 + lane;
  float* ab = aout + (size_t)i * (50496u * 256u);
  int mm[5]; bool mv[5];
  #pragma unroll
  for (int j = 0; j < 5; ++j) {
    int m = lane + j * 64;
    mv[j] = m < NN;
    mm[j] = mv[j] ? m : NN - 1;
  }
  for (int n = wave; n < NN; n += 4) {
    float qv = (lane < 32) ? base[(size_t)n * 768 + h * 64 + i * 32 + lane] : 0.f;
    float s[5] = {0.f, 0.f, 0.f, 0.f, 0.f};
    #pragma unroll
    for (int k = 0; k < 32; ++k) {
      float qk = __shfl(qv, k, 64);
      #pragma unroll
      for (int j = 0; j < 5; ++j)
        s[j] = fmaf(qk, ks[k * NN + mm[j]], s[j]);
    }
    const float sc = 0.17677669529663687f;  // 1/sqrt(32)
    float mx = -1e30f;
    #pragma unroll
    for (int j = 0; j < 5; ++j) { s[j] *= sc; if (mv[j]) mx = fmaxf(mx, s[j]); }
    mx = wred_max(mx);
    float sum = 0.f;
    #pragma unroll
    for (int j = 0; j < 5; ++j) { s[j] = mv[j] ? __expf(s[j] - mx) : 0.f; sum += s[j]; }
    sum = wred_sum(sum);
    float inv = 1.f / sum;
    #pragma unroll
    for (int j = 0; j < 5; ++j)
      if (mv[j]) prow[wave * 264 + lane + j * 64] = s[j] * inv;
    // per-wave LDS: DS pipe is in-order per wave -> no barrier needed
    float a = 0.f;
    for (int m = 0; m < NN; ++m)
      a = fmaf(prow[wave * 264 + m], vbase[(size_t)m * 768], a);
    ab[((size_t)(bt * NN + n) * 4 + h) * 64 + lane] = a;
  }
}

// ---------------------------------------------------------------------------
// s_x = LayerNorm(a1 - lam*a2) * g * 0.8 + b * 0.8   (per (btn,h), width 64)
// ---------------------------------------------------------------------------
__global__ __launch_bounds__(256) void diff_ln(
    const float* __restrict__ a1, const float* __restrict__ a2,
    const float* __restrict__ lamp,
    const float* __restrict__ g, const float* __restrict__ b,
    float* __restrict__ st)
{
  const int btn = blockIdx.x;
  const int lane = threadIdx.x & 63;
  const int h = threadIdx.x >> 6;
  const float lam = lamp[0];
  size_t off = ((size_t)btn * 4 + h) * 64 + lane;
  float y = a1[off] - lam * a2[off];
  float mean = wred_sum(y) * (1.f / 64.f);
  float t = y - mean;
  float var = wred_sum(t * t) * (1.f / 64.f);
  float r = rsqrtf(var + 1e-5f);
  st[(size_t)btn * 640 + h * 64 + lane] = (t * r * g[lane] + b[lane]) * 0.8f;
}

// ---------------------------------------------------------------------------
// Temporal attention over T=24 per (b,n,h):
// qkvt row: [q_t(128)|k_t(128)|v_t(128)|k_tg(128)|v_tg(128)], writes st[384:512]
// ---------------------------------------------------------------------------
__global__ __launch_bounds__(256) void temporal_attn(
    const float* __restrict__ qkvt, float* __restrict__ st)
{
  __shared__ float kt[2 * 24 * 65];
  __shared__ float vt[2 * 24 * 65];
  const int b = blockIdx.x / NN;
  const int n = blockIdx.x % NN;
  const int tid = threadIdx.x;
  const int lane = tid & 63;
  const int wave = tid >> 6;
  for (int idx = tid; idx < 2 * 24 * 64; idx += 256) {
    int t = idx >> 7, hd = idx & 127, h = hd >> 6, d = hd & 63;
    size_t row = ((size_t)(b * TT + t) * NN + n) * 640;
    kt[(h * 24 + t) * 65 + d] = qkvt[row + 128 + h * 64 + d];
    vt[(h * 24 + t) * 65 + d] = qkvt[row + 256 + h * 64 + d];
  }
  __syncthreads();
  for (int r = wave; r < 48; r += 4) {
    int t = r >> 1, h = r & 1;
    size_t row = ((size_t)(b * TT + t) * NN + n) * 640;
    float qv = qkvt[row + h * 64 + lane];
    int ss = lane < 24 ? lane : 23;
    float sc_ = 0.f;
    #pragma unroll
    for (int d = 0; d < 64; ++d) {
      float qd = __shfl(qv, d, 64);
      sc_ = fmaf(qd, kt[(h * 24 + ss) * 65 + d], sc_);
    }
    sc_ *= 0.125f;  // 1/sqrt(64)
    bool valid = lane < 24;
    float mx = wred_max(valid ? sc_ : -1e30f);
    float p = valid ? __expf(sc_ - mx) : 0.f;
    float inv = 1.f / wred_sum(p);
    float o = 0.f;
    #pragma unroll
    for (int s = 0; s < 24; ++s) {
      float ps = __shfl(p, s, 64);
      o = fmaf(ps, vt[(h * 24 + s) * 65 + lane], o);
    }
    st[row + 384 + h * 64 + lane] = o * inv;
  }
}

// ---------------------------------------------------------------------------
// Temporal-global: pg = softmax_t(qg[n,s]·kg[b,t,n]), tgx = pg@vg,
// tg[b,t,n] = sum_s tmp_map[b,n,t,s]*tgx[b,n,s]. Writes st[512:640].
// ---------------------------------------------------------------------------
__global__ __launch_bounds__(256) void tglobal_attn(
    const float* __restrict__ qkvt, const float* __restrict__ q_agg,
    const float* __restrict__ tmp_map, float* __restrict__ st)
{
  __shared__ float kg[2 * 24 * 65];
  __shared__ float vg[2 * 24 * 65];
  __shared__ float tgx[12 * 128];
  const int b = blockIdx.x / NN;
  const int n = blockIdx.x % NN;
  const int tid = threadIdx.x;
  const int lane = tid & 63;
  const int wave = tid >> 6;
  for (int idx = tid; idx < 2 * 24 * 64; idx += 256) {
    int t = idx >> 7, hd = idx & 127, h = hd >> 6, d = hd & 63;
    size_t row = ((size_t)(b * TT + t) * NN + n) * 640;
    kg[(h * 24 + t) * 65 + d] = qkvt[row + 384 + h * 64 + d];
    vg[(h * 24 + t) * 65 + d] = qkvt[row + 512 + h * 64 + d];
  }
  __syncthreads();
  for (int r = wave; r < 24; r += 4) {
    int s = r >> 1, h = r & 1;
    float qv = q_agg[((size_t)n * 12 + s) * 128 + h * 64 + lane];
    int tc = lane < 24 ? lane : 23;
    float sc_ = 0.f;
    #pragma unroll
    for (int d = 0; d < 64; ++d) {
      float qd = __shfl(qv, d, 64);
      sc_ = fmaf(qd, kg[(h * 24 + tc) * 65 + d], sc_);
    }
    sc_ *= 0.125f;
    bool valid = lane < 24;
    float mx = wred_max(valid ? sc_ : -1e30f);
    float p = valid ? __expf(sc_ - mx) : 0.f;
    float inv = 1.f / wred_sum(p);
    float o = 0.f;
    #pragma unroll
    for (int t = 0; t < 24; ++t) {
      float pt = __shfl(p, t, 64);
      o = fmaf(pt, vg[(h * 24 + t) * 65 + lane], o);
    }
    tgx[s * 128 + h * 64 + lane] = o * inv;
  }
  __syncthreads();
  for (int idx = tid; idx < 24 * 128; idx += 256) {
    int t = idx >> 7, c = idx & 127;
    const float* tm = tmp_map + ((size_t)(b * NN + n) * TT + t) * 12;
    float acc = 0.f;
    #pragma unroll
    for (int s = 0; s < 12; ++s) acc = fmaf(tm[s], tgx[s * 128 + c], acc);
    st[((size_t)(b * TT + t) * NN + n) * 640 + 512 + c] = acc;
  }
}

// ---------------------------------------------------------------------------
// Aggregate-branch attention: per (b,t,h), Ni in {32,64}, dh=64.
// qkva row: [q(128)|k(128)|v(128)]. Writes sx[(bt*Ni+n)*128 + h*64+d].
// ---------------------------------------------------------------------------
__global__ __launch_bounds__(256) void agg_attn(
    const float* __restrict__ qkva, float* __restrict__ sx, int Ni)
{
  __shared__ float kT[64 * 64];
  __shared__ float vl[64 * 64];
  const int h = blockIdx.x & 1;
  const int bt = blockIdx.x >> 1;
  const int tid = threadIdx.x;
  const int lane = tid & 63;
  const int wave = tid >> 6;
  for (int idx = tid; idx < Ni * 64; idx += 256) {
    int m = idx >> 6, d = idx & 63;
    size_t row = (size_t)(bt * Ni + m) * 384;
    kT[d * Ni + m] = qkva[row + 128 + h * 64 + d];
    vl[m * 64 + d] = qkva[row + 256 + h * 64 + d];
  }
  __syncthreads();
  int mc = lane < Ni ? lane : Ni - 1;
  bool valid = lane < Ni;
  for (int n = wave; n < Ni; n += 4) {
    float qv = qkva[(size_t)(bt * Ni + n) * 384 + h * 64 + lane];
    float sc_ = 0.f;
    #pragma unroll
    for (int d = 0; d < 64; ++d) {
      float qd = __shfl(qv, d, 64);
      sc_ = fmaf(qd, kT[d * Ni + mc], sc_);
    }
    sc_ *= 0.125f;
    float mx = wred_max(valid ? sc_ : -1e30f);
    float p = valid ? __expf(sc_ - mx) : 0.f;
    float inv = 1.f / wred_sum(p);
    float o = 0.f;
    for (int m = 0; m < Ni; ++m) {
      float pm = __shfl(p, m, 64);
      o = fmaf(pm, vl[m * 64 + lane], o);
    }
    sx[(size_t)(bt * Ni + n) * 128 + h * 64 + lane] = o * inv;
  }
}

// ---------------------------------------------------------------------------
// M-map: sg_pre[bt,n,c] = sum_m M0[m,n]*sx0[bt,m,c] + sum_m M1[m,n]*sx1[bt,m,c]
// ---------------------------------------------------------------------------
__global__ __launch_bounds__(256) void mmap_kernel(
    const float* __restrict__ sx0, const float* __restrict__ sx1,
    const float* __restrict__ M0, const float* __restrict__ M1,
    float* __restrict__ sg)
{
  __shared__ float s0[32 * 128];
  __shared__ float s1[64 * 128];
  const int bt = blockIdx.x;
  const int chunk = blockIdx.y;
  const int tid = threadIdx.x;
  for (int idx = tid; idx < 32 * 128; idx += 256) s0[idx] = sx0[(size_t)bt * 32 * 128 + idx];
  for (int idx = tid; idx < 64 * 128; idx += 256) s1[idx] = sx1[(size_t)bt * 64 * 128 + idx];
  __syncthreads();
  for (int idx = tid; idx < 88 * 128; idx += 256) {
    int n = chunk * 88 + (idx >> 7);
    if (n < NN) {
      int c = idx & 127;
      float acc = 0.f;
      #pragma unroll
      for (int m = 0; m < 32; ++m) acc = fmaf(M0[m * NN + n], s0[m * 128 + c], acc);
      #pragma unroll
      for (int m = 0; m < 64; ++m) acc = fmaf(M1[m * NN + n], s1[m * 128 + c], acc);
      sg[((size_t)bt * NN + n) * 128 + c] = acc;
    }
  }
}

// ---------------------------------------------------------------------------
extern "C" void kernel_launch(void* const* d_in, const int* in_sizes, int n_in,
                              void* d_out, int out_size, void* d_ws, size_t ws_size,
                              hipStream_t stream)
{
  const float* x       = (const float*)d_in[0];
  const float* agg_x0  = (const float*)d_in[1];
  const float* agg_x1  = (const float*)d_in[2];
  const float* tmp_map = (const float*)d_in[3];
  const float* Wq_s = (const float*)d_in[4];
  const float* Wk_s = (const float*)d_in[5];
  const float* Wv_s = (const float*)d_in[6];
  const float* lq1 = (const float*)d_in[7];
  const float* lk1 = (const float*)d_in[8];
  const float* lq2 = (const float*)d_in[9];
  const float* lk2 = (const float*)d_in[10];
  const float* ln_g = (const float*)d_in[11];
  const float* ln_b = (const float*)d_in[12];
  const float* Wq_a0 = (const float*)d_in[13];
  const float* Wk_a0 = (const float*)d_in[14];
  const float* Wv_a0 = (const float*)d_in[15];
  const float* Wq_a1 = (const float*)d_in[16];
  const float* Wk_a1 = (const float*)d_in[17];
  const float* Wv_a1 = (const float*)d_in[18];
  const float* M0   = (const float*)d_in[19];
  const float* M1   = (const float*)d_in[20];
  const float* Wagg = (const float*)d_in[21];
  const float* bagg = (const float*)d_in[22];
  const float* Wq_t = (const float*)d_in[23];
  const float* Wk_t = (const float*)d_in[24];
  const float* Wv_t = (const float*)d_in[25];
  const float* q_agg = (const float*)d_in[26];
  const float* Wk_tg = (const float*)d_in[27];
  const float* Wv_tg = (const float*)d_in[28];
  const float* Wout  = (const float*)d_in[29];
  const float* bout  = (const float*)d_in[30];
  float* ws  = (float*)d_ws;
  float* out = (float*)d_out;

  // workspace layout (floats) — region A: qkv_s then st; region B: a1/a2 then agg
  const size_t o_Wa0  = 720896;
  const size_t o_Wa1  = 917504;
  const size_t o_lam  = 1114112;
  const size_t o_A    = 1114128;
  const size_t o_qkvt = o_A + 38780928;      // 50496*768
  const size_t o_B    = o_qkvt + 32317440;   // 50496*640; total 98066448 fl = 374 MB

  float* W_all = ws;
  float* W_a0  = ws + o_Wa0;
  float* W_a1  = ws + o_Wa1;
  float* lamp  = ws + o_lam;
  float* qkv_s = ws + o_A;
  float* st    = ws + o_A;                   // aliases qkv_s (dead after diff_attn)
  float* qkvt  = ws + o_qkvt;
  float* a1    = ws + o_B;                   // region B phase 1
  float* qkva0 = ws + o_B;                   // region B phase 2 (after diff_ln)
  float* qkva1 = qkva0 + 2359296;
  float* sx0   = qkva0 + 7077888;
  float* sx1   = qkva0 + 7864320;
  float* sgp   = qkva0 + 9437184;

  auto cp = [&](float* dst, const float* src, size_t nfl) {
    hipMemcpyAsync(dst, src, nfl * sizeof(float), hipMemcpyDeviceToDevice, stream);
  };
  // W_all rows: [Wq_s|Wk_s|Wv_s|Wq_t|Wk_t|Wv_t|Wk_tg|Wv_tg], each row K=512
  cp(W_all + 0,      Wq_s, 131072);
  cp(W_all + 131072, Wk_s, 131072);
  cp(W_all + 262144, Wv_s, 131072);
  cp(W_all + 393216, Wq_t, 65536);
  cp(W_all + 458752, Wk_t, 65536);
  cp(W_all + 524288, Wv_t, 65536);
  cp(W_all + 589824, Wk_tg, 65536);
  cp(W_all + 655360, Wv_tg, 65536);
  cp(W_a0 + 0,      Wq_a0, 65536);
  cp(W_a0 + 65536,  Wk_a0, 65536);
  cp(W_a0 + 131072, Wv_a0, 65536);
  cp(W_a1 + 0,      Wq_a1, 65536);
  cp(W_a1 + 65536,  Wk_a1, 65536);
  cp(W_a1 + 131072, Wv_a1, 65536);

  hipLaunchKernelGGL(lam_kernel, dim3(1), dim3(64), 0, stream, lq1, lk1, lq2, lk2, lamp);

  const int Mx = 50496;  // B*T*N
  // 1) x -> qkv_s [50496 x 768]
  hipLaunchKernelGGL(gemm_nt, dim3(395, 6), dim3(256), 0, stream,
                     x, W_all, (const float*)nullptr, qkv_s, Mx, 768, 512, 768);
  // 2) differential attention halves -> a1 (i=0), a2 (i=1) in region B
  hipLaunchKernelGGL(diff_attn, dim3(768, 2), dim3(256), 0, stream, qkv_s, a1);
  // 3) x -> qkvt [50496 x 640]
  hipLaunchKernelGGL(gemm_nt, dim3(395, 5), dim3(256), 0, stream,
                     x, W_all + 393216, (const float*)nullptr, qkvt, Mx, 640, 512, 640);
  // 4) s_x = LN(a1 - lam*a2)*0.8 -> st[:,0:256] (overwrites qkv_s region — now dead)
  hipLaunchKernelGGL(diff_ln, dim3(Mx), dim3(256), 0, stream,
                     a1, a1 + 12926976, lamp, ln_g, ln_b, st);
  // 5) temporal attention -> st[:,384:512]
  hipLaunchKernelGGL(temporal_attn, dim3(8 * NN), dim3(256), 0, stream, qkvt, st);
  // 6) temporal-global -> st[:,512:640]
  hipLaunchKernelGGL(tglobal_attn, dim3(8 * NN), dim3(256), 0, stream, qkvt, q_agg, tmp_map, st);
  // 7) agg branches (region B reused — a1/a2 consumed by step 4)
  hipLaunchKernelGGL(gemm_nt, dim3(48, 3), dim3(256), 0, stream,
                     agg_x0, W_a0, (const float*)nullptr, qkva0, 6144, 384, 512, 384);
  hipLaunchKernelGGL(gemm_nt, dim3(96, 3), dim3(256), 0, stream,
                     agg_x1, W_a1, (const float*)nullptr, qkva1, 12288, 384, 512, 384);
  hipLaunchKernelGGL(agg_attn, dim3(384), dim3(256), 0, stream, qkva0, sx0, 32);
  hipLaunchKernelGGL(agg_attn, dim3(384), dim3(256), 0, stream, qkva1, sx1, 64);
  hipLaunchKernelGGL(mmap_kernel, dim3(192, 3), dim3(256), 0, stream, sx0, sx1, M0, M1, sgp);
  // 8) sg = sg_pre @ Wagg^T + bagg -> st[:,256:384]
  hipLaunchKernelGGL(gemm_nt, dim3(395, 1), dim3(256), 0, stream,
                     sgp, Wagg, bagg, st + 256, Mx, 128, 128, 640);
  // 9) out = st @ Wout^T + bout
  hipLaunchKernelGGL(gemm_nt, dim3(395, 4), dim3(256), 0, stream,
                     st, Wout, bout, out, Mx, 512, 640, 512);
}

// Round 3
// 2892.699 us; speedup vs baseline: 2.4076x; 2.4076x over previous
//
#include <hip/hip_runtime.h>

#define NN 263
#define TT 24

typedef __fp16 h2 __attribute__((ext_vector_type(2)));

static __device__ __forceinline__ float wred_sum(float v) {
  #pragma unroll
  for (int off = 32; off >= 1; off >>= 1) v += __shfl_xor(v, off, 64);
  return v;
}
static __device__ __forceinline__ float wred_max(float v) {
  #pragma unroll
  for (int off = 32; off >= 1; off >>= 1) v = fmaxf(v, __shfl_xor(v, off, 64));
  return v;
}
// broadcast a packed h2 from lane `l` to all lanes (VALU readlane, no DS traffic)
static __device__ __forceinline__ h2 rl_h2(h2 v, int l) {
  union { h2 h; int i; } u; u.h = v;
  u.i = __builtin_amdgcn_readlane(u.i, l);
  return u.h;
}
static __device__ __forceinline__ float rl_f(float v, int l) {
  union { float f; int i; } u; u.f = v;
  u.i = __builtin_amdgcn_readlane(u.i, l);
  return u.f;
}

// ---------------------------------------------------------------------------
// Generic fp32 NT GEMM: C[m,n] = sum_k A[m,k]*W[n,k] (+bias[n])
// ---------------------------------------------------------------------------
__global__ __launch_bounds__(256) void gemm_nt(
    const float* __restrict__ A, const float* __restrict__ W,
    const float* __restrict__ bias, float* __restrict__ C,
    int M, int N, int K, int ldc)
{
  __shared__ float As[16][132];
  __shared__ float Bs[16][132];
  const int bm = blockIdx.x * 128;
  const int bn = blockIdx.y * 128;
  const int tid = threadIdx.x;
  const int tx = tid & 15, ty = tid >> 4;
  float acc[8][8];
  #pragma unroll
  for (int i = 0; i < 8; ++i)
    #pragma unroll
    for (int j = 0; j < 8; ++j) acc[i][j] = 0.f;

  for (int k0 = 0; k0 < K; k0 += 16) {
    #pragma unroll
    for (int l = 0; l < 2; ++l) {
      int idx = tid + l * 256;
      int m = idx >> 2;
      int kq = (idx & 3) << 2;
      int gm = bm + m; if (gm > M - 1) gm = M - 1;
      float4 av = *(const float4*)(A + (size_t)gm * K + k0 + kq);
      As[kq + 0][m] = av.x; As[kq + 1][m] = av.y;
      As[kq + 2][m] = av.z; As[kq + 3][m] = av.w;
      int gn = bn + m; if (gn > N - 1) gn = N - 1;
      float4 bv = *(const float4*)(W + (size_t)gn * K + k0 + kq);
      Bs[kq + 0][m] = bv.x; Bs[kq + 1][m] = bv.y;
      Bs[kq + 2][m] = bv.z; Bs[kq + 3][m] = bv.w;
    }
    __syncthreads();
    #pragma unroll
    for (int k = 0; k < 16; ++k) {
      float a[8], b[8];
      #pragma unroll
      for (int i = 0; i < 8; ++i) a[i] = As[k][ty * 8 + i];
      #pragma unroll
      for (int j = 0; j < 8; ++j) b[j] = Bs[k][tx * 8 + j];
      #pragma unroll
      for (int i = 0; i < 8; ++i)
        #pragma unroll
        for (int j = 0; j < 8; ++j) acc[i][j] = fmaf(a[i], b[j], acc[i][j]);
    }
    __syncthreads();
  }
  #pragma unroll
  for (int i = 0; i < 8; ++i) {
    int gm = bm + ty * 8 + i;
    if (gm >= M) break;
    float* crow = C + (size_t)gm * ldc + bn;
    #pragma unroll
    for (int j = 0; j < 8; ++j) {
      int gn = bn + tx * 8 + j;
      if (gn < N) {
        float v = acc[i][j];
        if (bias) v += bias[gn];
        crow[tx * 8 + j] = v;
      }
    }
  }
}

// ---------------------------------------------------------------------------
__global__ void lam_kernel(const float* __restrict__ lq1, const float* __restrict__ lk1,
                           const float* __restrict__ lq2, const float* __restrict__ lk2,
                           float* __restrict__ out) {
  int lane = threadIdx.x;
  float v1 = lane < 32 ? lq1[lane] * lk1[lane] : 0.f;
  float v2 = lane < 32 ? lq2[lane] * lk2[lane] : 0.f;
  v1 = wred_sum(v1);
  v2 = wred_sum(v2);
  if (lane == 0) out[0] = expf(v1) - expf(v2) + 0.2f;
}

// ---------------------------------------------------------------------------
// Differential self-attention half, v2.
// Per block (bt,h,i): K-half cached in registers as f16x2 (lane l owns rows
// m = l+64j); V resident in LDS as f16 pairs over (m, m+64) matching the
// lane-strided P layout; QK and PV via v_dot2_f32_f16 (fp32 accumulate);
// P broadcast via v_readlane (VALU) — DS pipe only carries the 135
// conflict-free ds_read_b32 of V per row.
// ---------------------------------------------------------------------------
__global__ __launch_bounds__(256) void diff_attn(
    const float* __restrict__ qkv, float* __restrict__ aout)
{
  __shared__ h2 vp[135 * 64];   // vp[mp*64+d] = (v[m_lo][d], v[m_hi][d])
  const int h = blockIdx.x & 3;
  const int bt = blockIdx.x >> 2;
  const int i = blockIdx.y;
  const int tid = threadIdx.x;
  const int lane = tid & 63;
  const int wave = tid >> 6;
  const float* base  = qkv + (size_t)bt * NN * 768;
  const float* kbase = base + 256 + h * 64 + i * 32;
  const float* vbase = base + 512 + h * 64;

  // stage V: pairs (m, m+64) within each 128-row group; tail rows pair with 0
  for (int idx = tid; idx < 135 * 64; idx += 256) {
    int mp = idx >> 6, d = idx & 63;
    int m_lo = mp < 64 ? mp : (mp < 128 ? mp + 64 : mp + 128);
    float lo = vbase[(size_t)m_lo * 768 + d];
    float hi = (mp < 128) ? vbase[(size_t)(m_lo + 64) * 768 + d] : 0.f;
    vp[idx] = __builtin_amdgcn_cvt_pkrtz(lo, hi);
  }

  // register K-cache: lane l holds k rows m = l + 64j (j=0..4, clamped)
  h2 kc[5][16];
  #pragma unroll
  for (int j = 0; j < 5; ++j) {
    int m = lane + 64 * j; if (m > NN - 1) m = NN - 1;
    const float* kr = kbase + (size_t)m * 768;
    #pragma unroll
    for (int t = 0; t < 8; ++t) {
      float4 kv = *(const float4*)(kr + 4 * t);
      kc[j][2 * t]     = __builtin_amdgcn_cvt_pkrtz(kv.x, kv.y);
      kc[j][2 * t + 1] = __builtin_amdgcn_cvt_pkrtz(kv.z, kv.w);
    }
  }
  __syncthreads();

  float* ab = aout + (size_t)i * (50496ull * 256ull);
  const float sc = 0.17677669529663687f;  // 1/sqrt(32)

  for (int n = wave; n < NN; n += 4) {
    // q row -> f16x2 pairs broadcast to all lanes
    float qv = (lane < 32) ? base[(size_t)n * 768 + h * 64 + i * 32 + lane] : 0.f;
    h2 qp[16];
    #pragma unroll
    for (int kk = 0; kk < 16; ++kk)
      qp[kk] = __builtin_amdgcn_cvt_pkrtz(rl_f(qv, 2 * kk), rl_f(qv, 2 * kk + 1));
    // scores: 5 m-rows per lane, all from registers
    float s[5] = {0.f, 0.f, 0.f, 0.f, 0.f};
    #pragma unroll
    for (int kk = 0; kk < 16; ++kk)
      #pragma unroll
      for (int j = 0; j < 5; ++j)
        s[j] = __builtin_amdgcn_fdot2(qp[kk], kc[j][kk], s[j], false);
    float mx = -1e30f;
    #pragma unroll
    for (int j = 0; j < 5; ++j) {
      s[j] *= sc;
      if (lane + 64 * j >= NN) s[j] = -1e30f;
      mx = fmaxf(mx, s[j]);
    }
    mx = wred_max(mx);
    float sum = 0.f;
    #pragma unroll
    for (int j = 0; j < 5; ++j) { s[j] = __expf(s[j] - mx); sum += s[j]; }
    sum = wred_sum(sum);
    float inv = 1.f / sum;
    // pack P pairs matching vp pairing: (l, l+64), (l+128, l+192), (l+256, 0)
    h2 p01 = __builtin_amdgcn_cvt_pkrtz(s[0] * inv, s[1] * inv);
    h2 p23 = __builtin_amdgcn_cvt_pkrtz(s[2] * inv, s[3] * inv);
    h2 p4  = __builtin_amdgcn_cvt_pkrtz(s[4] * inv, 0.f);
    // PV: lane = d; readlane-broadcast P, ds_read V, dot2 accumulate
    float o0 = 0.f, o1 = 0.f, o2 = 0.f, o3 = 0.f;
    #pragma unroll
    for (int mp = 0; mp < 64; mp += 4) {
      o0 = __builtin_amdgcn_fdot2(rl_h2(p01, mp + 0), vp[(mp + 0) * 64 + lane], o0, false);
      o1 = __builtin_amdgcn_fdot2(rl_h2(p01, mp + 1), vp[(mp + 1) * 64 + lane], o1, false);
      o2 = __builtin_amdgcn_fdot2(rl_h2(p01, mp + 2), vp[(mp + 2) * 64 + lane], o2, false);
      o3 = __builtin_amdgcn_fdot2(rl_h2(p01, mp + 3), vp[(mp + 3) * 64 + lane], o3, false);
    }
    #pragma unroll
    for (int mp = 0; mp < 64; mp += 4) {
      o0 = __builtin_amdgcn_fdot2(rl_h2(p23, mp + 0), vp[(64 + mp + 0) * 64 + lane], o0, false);
      o1 = __builtin_amdgcn_fdot2(rl_h2(p23, mp + 1), vp[(64 + mp + 1) * 64 + lane], o1, false);
      o2 = __builtin_amdgcn_fdot2(rl_h2(p23, mp + 2), vp[(64 + mp + 2) * 64 + lane], o2, false);
      o3 = __builtin_amdgcn_fdot2(rl_h2(p23, mp + 3), vp[(64 + mp + 3) * 64 + lane], o3, false);
    }
    #pragma unroll
    for (int mp = 0; mp < 7; ++mp)
      o0 = __builtin_amdgcn_fdot2(rl_h2(p4, mp), vp[(128 + mp) * 64 + lane], o0, false);
    ab[((size_t)(bt * NN + n) * 4 + h) * 64 + lane] = (o0 + o1) + (o2 + o3);
  }
}

// ---------------------------------------------------------------------------
__global__ __launch_bounds__(256) void diff_ln(
    const float* __restrict__ a1, const float* __restrict__ a2,
    const float* __restrict__ lamp,
    const float* __restrict__ g, const float* __restrict__ b,
    float* __restrict__ st)
{
  const int btn = blockIdx.x;
  const int lane = threadIdx.x & 63;
  const int h = threadIdx.x >> 6;
  const float lam = lamp[0];
  size_t off = ((size_t)btn * 4 + h) * 64 + lane;
  float y = a1[off] - lam * a2[off];
  float mean = wred_sum(y) * (1.f / 64.f);
  float t = y - mean;
  float var = wred_sum(t * t) * (1.f / 64.f);
  float r = rsqrtf(var + 1e-5f);
  st[(size_t)btn * 640 + h * 64 + lane] = (t * r * g[lane] + b[lane]) * 0.8f;
}

// ---------------------------------------------------------------------------
__global__ __launch_bounds__(256) void temporal_attn(
    const float* __restrict__ qkvt, float* __restrict__ st)
{
  __shared__ float kt[2 * 24 * 65];
  __shared__ float vt[2 * 24 * 65];
  const int b = blockIdx.x / NN;
  const int n = blockIdx.x % NN;
  const int tid = threadIdx.x;
  const int lane = tid & 63;
  const int wave = tid >> 6;
  for (int idx = tid; idx < 2 * 24 * 64; idx += 256) {
    int t = idx >> 7, hd = idx & 127, h = hd >> 6, d = hd & 63;
    size_t row = ((size_t)(b * TT + t) * NN + n) * 640;
    kt[(h * 24 + t) * 65 + d] = qkvt[row + 128 + h * 64 + d];
    vt[(h * 24 + t) * 65 + d] = qkvt[row + 256 + h * 64 + d];
  }
  __syncthreads();
  for (int r = wave; r < 48; r += 4) {
    int t = r >> 1, h = r & 1;
    size_t row = ((size_t)(b * TT + t) * NN + n) * 640;
    float qv = qkvt[row + h * 64 + lane];
    int ss = lane < 24 ? lane : 23;
    float sc_ = 0.f;
    #pragma unroll
    for (int d = 0; d < 64; ++d) {
      float qd = __shfl(qv, d, 64);
      sc_ = fmaf(qd, kt[(h * 24 + ss) * 65 + d], sc_);
    }
    sc_ *= 0.125f;
    bool valid = lane < 24;
    float mx = wred_max(valid ? sc_ : -1e30f);
    float p = valid ? __expf(sc_ - mx) : 0.f;
    float inv = 1.f / wred_sum(p);
    float o = 0.f;
    #pragma unroll
    for (int s = 0; s < 24; ++s) {
      float ps = __shfl(p, s, 64);
      o = fmaf(ps, vt[(h * 24 + s) * 65 + lane], o);
    }
    st[row + 384 + h * 64 + lane] = o * inv;
  }
}

// ---------------------------------------------------------------------------
__global__ __launch_bounds__(256) void tglobal_attn(
    const float* __restrict__ qkvt, const float* __restrict__ q_agg,
    const float* __restrict__ tmp_map, float* __restrict__ st)
{
  __shared__ float kg[2 * 24 * 65];
  __shared__ float vg[2 * 24 * 65];
  __shared__ float tgx[12 * 128];
  const int b = blockIdx.x / NN;
  const int n = blockIdx.x % NN;
  const int tid = threadIdx.x;
  const int lane = tid & 63;
  const int wave = tid >> 6;
  for (int idx = tid; idx < 2 * 24 * 64; idx += 256) {
    int t = idx >> 7, hd = idx & 127, h = hd >> 6, d = hd & 63;
    size_t row = ((size_t)(b * TT + t) * NN + n) * 640;
    kg[(h * 24 + t) * 65 + d] = qkvt[row + 384 + h * 64 + d];
    vg[(h * 24 + t) * 65 + d] = qkvt[row + 512 + h * 64 + d];
  }
  __syncthreads();
  for (int r = wave; r < 24; r += 4) {
    int s = r >> 1, h = r & 1;
    float qv = q_agg[((size_t)n * 12 + s) * 128 + h * 64 + lane];
    int tc = lane < 24 ? lane : 23;
    float sc_ = 0.f;
    #pragma unroll
    for (int d = 0; d < 64; ++d) {
      float qd = __shfl(qv, d, 64);
      sc_ = fmaf(qd, kg[(h * 24 + tc) * 65 + d], sc_);
    }
    sc_ *= 0.125f;
    bool valid = lane < 24;
    float mx = wred_max(valid ? sc_ : -1e30f);
    float p = valid ? __expf(sc_ - mx) : 0.f;
    float inv = 1.f / wred_sum(p);
    float o = 0.f;
    #pragma unroll
    for (int t = 0; t < 24; ++t) {
      float pt = __shfl(p, t, 64);
      o = fmaf(pt, vg[(h * 24 + t) * 65 + lane], o);
    }
    tgx[s * 128 + h * 64 + lane] = o * inv;
  }
  __syncthreads();
  for (int idx = tid; idx < 24 * 128; idx += 256) {
    int t = idx >> 7, c = idx & 127;
    const float* tm = tmp_map + ((size_t)(b * NN + n) * TT + t) * 12;
    float acc = 0.f;
    #pragma unroll
    for (int s = 0; s < 12; ++s) acc = fmaf(tm[s], tgx[s * 128 + c], acc);
    st[((size_t)(b * TT + t) * NN + n) * 640 + 512 + c] = acc;
  }
}

// ---------------------------------------------------------------------------
__global__ __launch_bounds__(256) void agg_attn(
    const float* __restrict__ qkva, float* __restrict__ sx, int Ni)
{
  __shared__ float kT[64 * 64];
  __shared__ float vl[64 * 64];
  const int h = blockIdx.x & 1;
  const int bt = blockIdx.x >> 1;
  const int tid = threadIdx.x;
  const int lane = tid & 63;
  const int wave = tid >> 6;
  for (int idx = tid; idx < Ni * 64; idx += 256) {
    int m = idx >> 6, d = idx & 63;
    size_t row = (size_t)(bt * Ni + m) * 384;
    kT[d * Ni + m] = qkva[row + 128 + h * 64 + d];
    vl[m * 64 + d] = qkva[row + 256 + h * 64 + d];
  }
  __syncthreads();
  int mc = lane < Ni ? lane : Ni - 1;
  bool valid = lane < Ni;
  for (int n = wave; n < Ni; n += 4) {
    float qv = qkva[(size_t)(bt * Ni + n) * 384 + h * 64 + lane];
    float sc_ = 0.f;
    #pragma unroll
    for (int d = 0; d < 64; ++d) {
      float qd = __shfl(qv, d, 64);
      sc_ = fmaf(qd, kT[d * Ni + mc], sc_);
    }
    sc_ *= 0.125f;
    float mx = wred_max(valid ? sc_ : -1e30f);
    float p = valid ? __expf(sc_ - mx) : 0.f;
    float inv = 1.f / wred_sum(p);
    float o = 0.f;
    for (int m = 0; m < Ni; ++m) {
      float pm = __shfl(p, m, 64);
      o = fmaf(pm, vl[m * 64 + lane], o);
    }
    sx[(size_t)(bt * Ni + n) * 128 + h * 64 + lane] = o * inv;
  }
}

// ---------------------------------------------------------------------------
__global__ __launch_bounds__(256) void mmap_kernel(
    const float* __restrict__ sx0, const float* __restrict__ sx1,
    const float* __restrict__ M0, const float* __restrict__ M1,
    float* __restrict__ sg)
{
  __shared__ float s0[32 * 128];
  __shared__ float s1[64 * 128];
  const int bt = blockIdx.x;
  const int chunk = blockIdx.y;
  const int tid = threadIdx.x;
  for (int idx = tid; idx < 32 * 128; idx += 256) s0[idx] = sx0[(size_t)bt * 32 * 128 + idx];
  for (int idx = tid; idx < 64 * 128; idx += 256) s1[idx] = sx1[(size_t)bt * 64 * 128 + idx];
  __syncthreads();
  for (int idx = tid; idx < 88 * 128; idx += 256) {
    int n = chunk * 88 + (idx >> 7);
    if (n < NN) {
      int c = idx & 127;
      float acc = 0.f;
      #pragma unroll
      for (int m = 0; m < 32; ++m) acc = fmaf(M0[m * NN + n], s0[m * 128 + c], acc);
      #pragma unroll
      for (int m = 0; m < 64; ++m) acc = fmaf(M1[m * NN + n], s1[m * 128 + c], acc);
      sg[((size_t)bt * NN + n) * 128 + c] = acc;
    }
  }
}

// ---------------------------------------------------------------------------
extern "C" void kernel_launch(void* const* d_in, const int* in_sizes, int n_in,
                              void* d_out, int out_size, void* d_ws, size_t ws_size,
                              hipStream_t stream)
{
  const float* x       = (const float*)d_in[0];
  const float* agg_x0  = (const float*)d_in[1];
  const float* agg_x1  = (const float*)d_in[2];
  const float* tmp_map = (const float*)d_in[3];
  const float* Wq_s = (const float*)d_in[4];
  const float* Wk_s = (const float*)d_in[5];
  const float* Wv_s = (const float*)d_in[6];
  const float* lq1 = (const float*)d_in[7];
  const float* lk1 = (const float*)d_in[8];
  const float* lq2 = (const float*)d_in[9];
  const float* lk2 = (const float*)d_in[10];
  const float* ln_g = (const float*)d_in[11];
  const float* ln_b = (const float*)d_in[12];
  const float* Wq_a0 = (const float*)d_in[13];
  const float* Wk_a0 = (const float*)d_in[14];
  const float* Wv_a0 = (const float*)d_in[15];
  const float* Wq_a1 = (const float*)d_in[16];
  const float* Wk_a1 = (const float*)d_in[17];
  const float* Wv_a1 = (const float*)d_in[18];
  const float* M0   = (const float*)d_in[19];
  const float* M1   = (const float*)d_in[20];
  const float* Wagg = (const float*)d_in[21];
  const float* bagg = (const float*)d_in[22];
  const float* Wq_t = (const float*)d_in[23];
  const float* Wk_t = (const float*)d_in[24];
  const float* Wv_t = (const float*)d_in[25];
  const float* q_agg = (const float*)d_in[26];
  const float* Wk_tg = (const float*)d_in[27];
  const float* Wv_tg = (const float*)d_in[28];
  const float* Wout  = (const float*)d_in[29];
  const float* bout  = (const float*)d_in[30];
  float* ws  = (float*)d_ws;
  float* out = (float*)d_out;

  const size_t o_Wa0  = 720896;
  const size_t o_Wa1  = 917504;
  const size_t o_lam  = 1114112;
  const size_t o_A    = 1114128;
  const size_t o_qkvt = o_A + 38780928;
  const size_t o_B    = o_qkvt + 32317440;

  float* W_all = ws;
  float* W_a0  = ws + o_Wa0;
  float* W_a1  = ws + o_Wa1;
  float* lamp  = ws + o_lam;
  float* qkv_s = ws + o_A;
  float* st    = ws + o_A;
  float* qkvt  = ws + o_qkvt;
  float* a1    = ws + o_B;
  float* qkva0 = ws + o_B;
  float* qkva1 = qkva0 + 2359296;
  float* sx0   = qkva0 + 7077888;
  float* sx1   = qkva0 + 7864320;
  float* sgp   = qkva0 + 9437184;

  auto cp = [&](float* dst, const float* src, size_t nfl) {
    (void)hipMemcpyAsync(dst, src, nfl * sizeof(float), hipMemcpyDeviceToDevice, stream);
  };
  cp(W_all + 0,      Wq_s, 131072);
  cp(W_all + 131072, Wk_s, 131072);
  cp(W_all + 262144, Wv_s, 131072);
  cp(W_all + 393216, Wq_t, 65536);
  cp(W_all + 458752, Wk_t, 65536);
  cp(W_all + 524288, Wv_t, 65536);
  cp(W_all + 589824, Wk_tg, 65536);
  cp(W_all + 655360, Wv_tg, 65536);
  cp(W_a0 + 0,      Wq_a0, 65536);
  cp(W_a0 + 65536,  Wk_a0, 65536);
  cp(W_a0 + 131072, Wv_a0, 65536);
  cp(W_a1 + 0,      Wq_a1, 65536);
  cp(W_a1 + 65536,  Wk_a1, 65536);
  cp(W_a1 + 131072, Wv_a1, 65536);

  hipLaunchKernelGGL(lam_kernel, dim3(1), dim3(64), 0, stream, lq1, lk1, lq2, lk2, lamp);

  const int Mx = 50496;
  hipLaunchKernelGGL(gemm_nt, dim3(395, 6), dim3(256), 0, stream,
                     x, W_all, (const float*)nullptr, qkv_s, Mx, 768, 512, 768);
  hipLaunchKernelGGL(diff_attn, dim3(768, 2), dim3(256), 0, stream, qkv_s, a1);
  hipLaunchKernelGGL(gemm_nt, dim3(395, 5), dim3(256), 0, stream,
                     x, W_all + 393216, (const float*)nullptr, qkvt, Mx, 640, 512, 640);
  hipLaunchKernelGGL(diff_ln, dim3(Mx), dim3(256), 0, stream,
                     a1, a1 + 12926976, lamp, ln_g, ln_b, st);
  hipLaunchKernelGGL(temporal_attn, dim3(8 * NN), dim3(256), 0, stream, qkvt, st);
  hipLaunchKernelGGL(tglobal_attn, dim3(8 * NN), dim3(256), 0, stream, qkvt, q_agg, tmp_map, st);
  hipLaunchKernelGGL(gemm_nt, dim3(48, 3), dim3(256), 0, stream,
                     agg_x0, W_a0, (const float*)nullptr, qkva0, 6144, 384, 512, 384);
  hipLaunchKernelGGL(gemm_nt, dim3(96, 3), dim3(256), 0, stream,
                     agg_x1, W_a1, (const float*)nullptr, qkva1, 12288, 384, 512, 384);
  hipLaunchKernelGGL(agg_attn, dim3(384), dim3(256), 0, stream, qkva0, sx0, 32);
  hipLaunchKernelGGL(agg_attn, dim3(384), dim3(256), 0, stream, qkva1, sx1, 64);
  hipLaunchKernelGGL(mmap_kernel, dim3(192, 3), dim3(256), 0, stream, sx0, sx1, M0, M1, sgp);
  hipLaunchKernelGGL(gemm_nt, dim3(395, 1), dim3(256), 0, stream,
                     sgp, Wagg, bagg, st + 256, Mx, 128, 128, 640);
  hipLaunchKernelGGL(gemm_nt, dim3(395, 4), dim3(256), 0, stream,
                     st, Wout, bout, out, Mx, 512, 640, 512);
}